// Round 6
// baseline (2365.125 us; speedup 1.0000x reference)
//
#include <hip/hip_runtime.h>
#include <math.h>

#define DMODEL 1024
#define DFF    4096
#define NE     8
#define EPSF   1.1920929e-07f

typedef float f4    __attribute__((ext_vector_type(4)));
typedef float f32x4 __attribute__((ext_vector_type(4)));
typedef short s16x8 __attribute__((ext_vector_type(8)));
typedef unsigned short u16x4 __attribute__((ext_vector_type(4)));

__device__ inline unsigned short bf16_rne(float f) {
  unsigned int u = __float_as_uint(f);
  u += 0x7fffu + ((u >> 16) & 1u);
  return (unsigned short)(u >> 16);
}
__device__ inline float bf16_up(unsigned short h) {
  return __uint_as_float(((unsigned int)h) << 16);
}

// ---------------- init ------------------------------------------------------
__global__ void moe_init(int* __restrict__ used_count, int* __restrict__ row_tok, int n_row) {
  int i = blockIdx.x * blockDim.x + threadIdx.x;
  if (i < NE) used_count[i] = 0;
  for (int j = i; j < n_row; j += gridDim.x * blockDim.x) row_tok[j] = -1;
}

// ---------------- router: softmax -> top2 -> renormalize --------------------
// one wave per token; routing decisions in full fp32 (must match reference)
__global__ __launch_bounds__(256)
void moe_router(const float* __restrict__ x, const float* __restrict__ rw,
                int* __restrict__ assign_e, float* __restrict__ assign_w, int T) {
  int gw = (int)((blockIdx.x * blockDim.x + threadIdx.x) >> 6);
  int lane = threadIdx.x & 63;
  if (gw >= T) return;
  const float* h = x + (size_t)gw * DMODEL;
  float acc[NE];
#pragma unroll
  for (int e = 0; e < NE; ++e) acc[e] = 0.f;
  for (int i = lane; i < DMODEL; i += 64) {
    float hv = h[i];
#pragma unroll
    for (int e = 0; e < NE; ++e) acc[e] = fmaf(hv, rw[e * DMODEL + i], acc[e]);
  }
#pragma unroll
  for (int e = 0; e < NE; ++e) {
    float v = acc[e];
    for (int o = 32; o > 0; o >>= 1) v += __shfl_xor(v, o, 64);
    acc[e] = v;
  }
  if (lane == 0) {
    float mx = acc[0];
#pragma unroll
    for (int e = 1; e < NE; ++e) mx = fmaxf(mx, acc[e]);
    float p[NE];
    float s = 0.f;
#pragma unroll
    for (int e = 0; e < NE; ++e) { p[e] = expf(acc[e] - mx); s += p[e]; }
#pragma unroll
    for (int e = 0; e < NE; ++e) p[e] /= s;
    // top-2, ties -> lowest index (matches jax.lax.top_k)
    int e0 = 0;
#pragma unroll
    for (int e = 1; e < NE; ++e) if (p[e] > p[e0]) e0 = e;
    int e1 = (e0 == 0) ? 1 : 0;
#pragma unroll
    for (int e = 0; e < NE; ++e) { if (e != e0 && p[e] > p[e1]) e1 = e; }
    float w0 = p[e0], w1 = p[e1];
    float wsum = fmaxf(w0 + w1, EPSF);
    assign_e[2 * gw] = e0;
    assign_e[2 * gw + 1] = e1;
    assign_w[2 * gw] = w0 / wsum;
    assign_w[2 * gw + 1] = w1 / wsum;
  }
}

// ---------------- rank/capacity: stable rank within expert ------------------
// keep iff rank (weight desc, flat-idx asc, within expert) < cap; slot == rank
// kept slots per expert are exactly 0..used-1 (contiguous)
__global__ __launch_bounds__(256)
void moe_rank(const int* __restrict__ assign_e, const float* __restrict__ assign_w,
              int* __restrict__ assign_slot, int* __restrict__ row_tok,
              int* __restrict__ used_count, int A, int cap) {
  int gw = (int)((blockIdx.x * blockDim.x + threadIdx.x) >> 6);
  int lane = threadIdx.x & 63;
  if (gw >= A) return;
  int e = assign_e[gw];
  float w = assign_w[gw];
  int cnt = 0;
  for (int j = lane; j < A; j += 64) {
    int ej = assign_e[j];
    float wj = assign_w[j];
    if (ej == e && (wj > w || (wj == w && j < gw))) cnt++;
  }
  for (int o = 32; o > 0; o >>= 1) cnt += __shfl_xor(cnt, o, 64);
  if (lane == 0) {
    if (cnt < cap) {
      assign_slot[gw] = cnt;
      row_tok[e * cap + cnt] = gw >> 1;
      atomicAdd(used_count + e, 1);
    } else {
      assign_slot[gw] = -1;
    }
  }
}

// ---------------- split: fp32 -> bf16 hi + bf16 lo (residual) ---------------
__global__ __launch_bounds__(256)
void moe_split(const float* __restrict__ src, unsigned short* __restrict__ hi,
               unsigned short* __restrict__ lo, long n4) {
  long i = (long)blockIdx.x * 256 + threadIdx.x;
  long stride = (long)gridDim.x * 256;
  for (; i < n4; i += stride) {
    f4 v = ((const f4*)src)[i];
    u16x4 h, l;
#pragma unroll
    for (int j = 0; j < 4; ++j) {
      unsigned short hb = bf16_rne(v[j]);
      h[j] = hb;
      l[j] = bf16_rne(v[j] - bf16_up(hb));
    }
    ((u16x4*)hi)[i] = h;
    ((u16x4*)lo)[i] = l;
  }
}

// LDS tile layout (per tile: [128 rows][32 k] bf16 = 8KB):
//   16B chunk (row r, k-chunk c in 0..3) stored at physical chunk r*4 + (c ^ ((r>>1)&3)).
//   Write: thread q owns physical chunk q -> logical r=q>>2, c=(q&3)^((q>>3)&3). Linear
//     16B/thread writes = 2-way per 16-lane phase (free, m136).
//   Read (frag): lane reads row base+(lane&15), chunk (lane>>4)^(((lane&15)>>1)&3);
//     swizzle term depends only on lane&15 bits 1-2, invariant under fm*16/wm*64 offsets
//     (those touch row bits >=4 only). Lanes 0-7 span all 32 banks once -> 2-way, free.

// ---------------- ffn1: mid = pre * silu(gate), bf16x3 MFMA -----------------
// acc += Ah*Bh + Ah*Bl + Al*Bh  (error ~2^-16 rel; fp32 accumulate)
__global__ __launch_bounds__(512, 2)
void moe_ffn1_mfma(const unsigned short* __restrict__ xh, const unsigned short* __restrict__ xl,
                   const unsigned short* __restrict__ wph, const unsigned short* __restrict__ wpl,
                   const unsigned short* __restrict__ wgh, const unsigned short* __restrict__ wgl,
                   const int* __restrict__ row_tok, const int* __restrict__ used_count,
                   unsigned short* __restrict__ midh, unsigned short* __restrict__ midl,
                   int e_base, int cap) {
  const int z = blockIdx.z;
  const int e = e_base + z;
  const int used = used_count[e];
  const int m0 = blockIdx.x * 128;
  if (m0 >= used) return;
  const int n0 = blockIdx.y * 128;

  __shared__ unsigned short lds[6 * 4096];  // A_h A_l P_h P_l G_h G_l

  const int tid = threadIdx.x;
  // staging role: thread owns physical chunk tid
  const int sr = tid >> 2;
  const int sc = (tid & 3) ^ ((tid >> 3) & 3);
  int arow = m0 + sr; if (arow >= cap) arow = cap - 1;
  int tokr = row_tok[e * cap + arow]; if (tokr < 0) tokr = 0;  // garbage row, never gathered
  const unsigned short* gAh = xh + (size_t)tokr * DMODEL + sc * 8;
  const unsigned short* gAl = xl + (size_t)tokr * DMODEL + sc * 8;
  const size_t wrow = ((size_t)z * DFF + n0 + sr) * DMODEL + sc * 8;
  const unsigned short* gPh = wph + wrow;
  const unsigned short* gPl = wpl + wrow;
  const unsigned short* gGh = wgh + wrow;
  const unsigned short* gGl = wgl + wrow;

  // fragment roles
  const int lane = tid & 63;
  const int wid = tid >> 6;
  const int wm = wid >> 2;     // 0..1
  const int wn = wid & 3;      // 0..3
  const int lr = lane & 15;
  const int lg = lane >> 4;
  const int swz = (lr >> 1) & 3;
  const int aoff = (wm * 64 + lr) * 32 + ((lg ^ swz) * 8);
  const int boff = (wn * 32 + lr) * 32 + ((lg ^ swz) * 8);

  f32x4 accP[4][2] = {};
  f32x4 accG[4][2] = {};

  for (int kk = 0; kk < DMODEL; kk += 32) {
    s16x8 vAh = *(const s16x8*)(gAh + kk);
    s16x8 vAl = *(const s16x8*)(gAl + kk);
    s16x8 vPh = *(const s16x8*)(gPh + kk);
    s16x8 vPl = *(const s16x8*)(gPl + kk);
    s16x8 vGh = *(const s16x8*)(gGh + kk);
    s16x8 vGl = *(const s16x8*)(gGl + kk);
    __syncthreads();
    *(s16x8*)&lds[0 * 4096 + tid * 8] = vAh;
    *(s16x8*)&lds[1 * 4096 + tid * 8] = vAl;
    *(s16x8*)&lds[2 * 4096 + tid * 8] = vPh;
    *(s16x8*)&lds[3 * 4096 + tid * 8] = vPl;
    *(s16x8*)&lds[4 * 4096 + tid * 8] = vGh;
    *(s16x8*)&lds[5 * 4096 + tid * 8] = vGl;
    __syncthreads();
    s16x8 ah[4], al[4];
#pragma unroll
    for (int fm = 0; fm < 4; ++fm) {
      ah[fm] = *(const s16x8*)&lds[0 * 4096 + aoff + fm * 512];
      al[fm] = *(const s16x8*)&lds[1 * 4096 + aoff + fm * 512];
    }
#pragma unroll
    for (int fn = 0; fn < 2; ++fn) {
      s16x8 bh = *(const s16x8*)&lds[2 * 4096 + boff + fn * 512];
      s16x8 bl = *(const s16x8*)&lds[3 * 4096 + boff + fn * 512];
      s16x8 ch = *(const s16x8*)&lds[4 * 4096 + boff + fn * 512];
      s16x8 cl = *(const s16x8*)&lds[5 * 4096 + boff + fn * 512];
#pragma unroll
      for (int fm = 0; fm < 4; ++fm) {
        accP[fm][fn] = __builtin_amdgcn_mfma_f32_16x16x32_bf16(ah[fm], bh, accP[fm][fn], 0, 0, 0);
        accP[fm][fn] = __builtin_amdgcn_mfma_f32_16x16x32_bf16(ah[fm], bl, accP[fm][fn], 0, 0, 0);
        accP[fm][fn] = __builtin_amdgcn_mfma_f32_16x16x32_bf16(al[fm], bh, accP[fm][fn], 0, 0, 0);
        accG[fm][fn] = __builtin_amdgcn_mfma_f32_16x16x32_bf16(ah[fm], ch, accG[fm][fn], 0, 0, 0);
        accG[fm][fn] = __builtin_amdgcn_mfma_f32_16x16x32_bf16(ah[fm], cl, accG[fm][fn], 0, 0, 0);
        accG[fm][fn] = __builtin_amdgcn_mfma_f32_16x16x32_bf16(al[fm], ch, accG[fm][fn], 0, 0, 0);
      }
    }
  }

  // C/D: col = lane&15, row = (lane>>4)*4 + reg  [m89-verified]
#pragma unroll
  for (int fm = 0; fm < 4; ++fm)
#pragma unroll
    for (int fn = 0; fn < 2; ++fn) {
      int m = m0 + wm * 64 + fm * 16 + lg * 4;
      int n = n0 + wn * 32 + fn * 16 + lr;
#pragma unroll
      for (int r = 0; r < 4; ++r) {
        if (m + r >= cap) continue;
        float gv = accG[fm][fn][r];
        float v = accP[fm][fn][r] * (gv / (1.f + expf(-gv)));
        size_t idx = ((size_t)z * cap + (m + r)) * DFF + n;
        unsigned short hb = bf16_rne(v);
        midh[idx] = hb;
        midl[idx] = bf16_rne(v - bf16_up(hb));
      }
    }
}

// ---------------- ffn2: eout = mid @ wpost^T, bf16x3 MFMA -------------------
__global__ __launch_bounds__(512, 2)
void moe_ffn2_mfma(const unsigned short* __restrict__ midh, const unsigned short* __restrict__ midl,
                   const unsigned short* __restrict__ wh, const unsigned short* __restrict__ wl,
                   const int* __restrict__ used_count, float* __restrict__ eout,
                   int e_base, int cap) {
  const int z = blockIdx.z;
  const int e = e_base + z;
  const int used = used_count[e];
  const int m0 = blockIdx.x * 128;
  if (m0 >= used) return;
  const int n0 = blockIdx.y * 128;

  __shared__ unsigned short lds[4 * 4096];  // A_h A_l B_h B_l

  const int tid = threadIdx.x;
  const int sr = tid >> 2;
  const int sc = (tid & 3) ^ ((tid >> 3) & 3);
  int arow = m0 + sr; if (arow >= cap) arow = cap - 1;
  const unsigned short* gAh = midh + ((size_t)z * cap + arow) * DFF + sc * 8;
  const unsigned short* gAl = midl + ((size_t)z * cap + arow) * DFF + sc * 8;
  const size_t wrow = ((size_t)z * DMODEL + n0 + sr) * DFF + sc * 8;
  const unsigned short* gBh = wh + wrow;
  const unsigned short* gBl = wl + wrow;

  const int lane = tid & 63;
  const int wid = tid >> 6;
  const int wm = wid >> 2;
  const int wn = wid & 3;
  const int lr = lane & 15;
  const int lg = lane >> 4;
  const int swz = (lr >> 1) & 3;
  const int aoff = (wm * 64 + lr) * 32 + ((lg ^ swz) * 8);
  const int boff = (wn * 32 + lr) * 32 + ((lg ^ swz) * 8);

  f32x4 acc[4][2] = {};

  for (int kk = 0; kk < DFF; kk += 32) {
    s16x8 vAh = *(const s16x8*)(gAh + kk);
    s16x8 vAl = *(const s16x8*)(gAl + kk);
    s16x8 vBh = *(const s16x8*)(gBh + kk);
    s16x8 vBl = *(const s16x8*)(gBl + kk);
    __syncthreads();
    *(s16x8*)&lds[0 * 4096 + tid * 8] = vAh;
    *(s16x8*)&lds[1 * 4096 + tid * 8] = vAl;
    *(s16x8*)&lds[2 * 4096 + tid * 8] = vBh;
    *(s16x8*)&lds[3 * 4096 + tid * 8] = vBl;
    __syncthreads();
    s16x8 ah[4], al[4];
#pragma unroll
    for (int fm = 0; fm < 4; ++fm) {
      ah[fm] = *(const s16x8*)&lds[0 * 4096 + aoff + fm * 512];
      al[fm] = *(const s16x8*)&lds[1 * 4096 + aoff + fm * 512];
    }
#pragma unroll
    for (int fn = 0; fn < 2; ++fn) {
      s16x8 bh = *(const s16x8*)&lds[2 * 4096 + boff + fn * 512];
      s16x8 bl = *(const s16x8*)&lds[3 * 4096 + boff + fn * 512];
#pragma unroll
      for (int fm = 0; fm < 4; ++fm) {
        acc[fm][fn] = __builtin_amdgcn_mfma_f32_16x16x32_bf16(ah[fm], bh, acc[fm][fn], 0, 0, 0);
        acc[fm][fn] = __builtin_amdgcn_mfma_f32_16x16x32_bf16(ah[fm], bl, acc[fm][fn], 0, 0, 0);
        acc[fm][fn] = __builtin_amdgcn_mfma_f32_16x16x32_bf16(al[fm], bh, acc[fm][fn], 0, 0, 0);
      }
    }
  }

#pragma unroll
  for (int fm = 0; fm < 4; ++fm)
#pragma unroll
    for (int fn = 0; fn < 2; ++fn) {
      int m = m0 + wm * 64 + fm * 16 + lg * 4;
      int n = n0 + wn * 32 + fn * 16 + lr;
#pragma unroll
      for (int r = 0; r < 4; ++r) {
        if (m + r >= cap) continue;
        eout[((size_t)e * cap + (m + r)) * DMODEL + n] = acc[fm][fn][r];
      }
    }
}

// ---------------- combine ---------------------------------------------------
__global__ __launch_bounds__(256)
void moe_combine(const float* __restrict__ eout, const int* __restrict__ assign_e,
                 const float* __restrict__ assign_w, const int* __restrict__ assign_slot,
                 float* __restrict__ out, int cap) {
  int t = blockIdx.x;
  int e0 = assign_e[2 * t], e1 = assign_e[2 * t + 1];
  float w0 = assign_w[2 * t], w1 = assign_w[2 * t + 1];
  int s0 = assign_slot[2 * t], s1 = assign_slot[2 * t + 1];
  float k0 = (s0 >= 0) ? w0 : 0.f;
  float k1 = (s1 >= 0) ? w1 : 0.f;
  float wsum = fmaxf(k0 + k1, EPSF);
  k0 /= wsum;
  k1 /= wsum;
  int i = threadIdx.x * 4;
  f4 v = {0.f, 0.f, 0.f, 0.f};
  if (s0 >= 0) v += k0 * *(const f4*)(eout + ((size_t)e0 * cap + s0) * DMODEL + i);
  if (s1 >= 0) v += k1 * *(const f4*)(eout + ((size_t)e1 * cap + s1) * DMODEL + i);
  *(f4*)(out + (size_t)t * DMODEL + i) = v;
}

extern "C" void kernel_launch(void* const* d_in, const int* in_sizes, int n_in,
                              void* d_out, int out_size, void* d_ws, size_t ws_size,
                              hipStream_t stream) {
  const float* x     = (const float*)d_in[0];
  const float* rw    = (const float*)d_in[1];
  const float* wpre  = (const float*)d_in[2];
  const float* wgate = (const float*)d_in[3];
  const float* wpost = (const float*)d_in[4];
  float* out = (float*)d_out;

  const int T = in_sizes[0] / DMODEL;
  const int A = T * 2;
  int cap = (int)ceil(1.25 * (double)A / NE);
  if (cap < 1) cap = 1;

  char* ws = (char*)d_ws;
  size_t off = 0;
  auto alloc = [&](size_t bytes) -> void* {
    void* p = ws + off;
    off += (bytes + 255) & ~(size_t)255;
    return p;
  };
  int*   assign_e    = (int*)alloc((size_t)A * 4);
  float* assign_w    = (float*)alloc((size_t)A * 4);
  int*   assign_slot = (int*)alloc((size_t)A * 4);
  int*   used_count  = (int*)alloc(NE * 4);
  int*   row_tok     = (int*)alloc((size_t)NE * cap * 4);
  float* eout        = (float*)alloc((size_t)NE * cap * DMODEL * 4);
  unsigned short* xh = (unsigned short*)alloc((size_t)T * DMODEL * 2);
  unsigned short* xl = (unsigned short*)alloc((size_t)T * DMODEL * 2);

  const size_t wE   = (size_t)NE * DFF * DMODEL;   // elements per weight tensor
  const size_t midE = (size_t)NE * cap * DFF;      // batched mid elements
  // bytes: 6 weight hi/lo arrays (2B/elem) + mid hi/lo; +64KB rounding slack
  const size_t needA = off + 12 * wE + 4 * midE + 65536;
  const bool pathA = ws_size >= needA;

  const int n_row = NE * cap;
  moe_init<<<dim3((n_row + 255) / 256), dim3(256), 0, stream>>>(used_count, row_tok, n_row);
  moe_router<<<dim3((T + 3) / 4), dim3(256), 0, stream>>>(x, rw, assign_e, assign_w, T);
  moe_rank<<<dim3((A + 3) / 4), dim3(256), 0, stream>>>(assign_e, assign_w, assign_slot,
                                                        row_tok, used_count, A, cap);
  long xq = (long)T * DMODEL / 4;
  moe_split<<<dim3((unsigned)((xq + 255) / 256 > 2048 ? 2048 : (xq + 255) / 256)),
              dim3(256), 0, stream>>>(x, xh, xl, xq);

  const int mt = (cap + 127) / 128;
  if (pathA) {
    unsigned short* wpreh  = (unsigned short*)alloc(wE * 2);
    unsigned short* wprel  = (unsigned short*)alloc(wE * 2);
    unsigned short* wgateh = (unsigned short*)alloc(wE * 2);
    unsigned short* wgatel = (unsigned short*)alloc(wE * 2);
    unsigned short* wposth = (unsigned short*)alloc(wE * 2);
    unsigned short* wpostl = (unsigned short*)alloc(wE * 2);
    unsigned short* midh   = (unsigned short*)alloc(midE * 2);
    unsigned short* midl   = (unsigned short*)alloc(midE * 2);
    long wq = (long)wE / 4;
    moe_split<<<dim3(2048), dim3(256), 0, stream>>>(wpre, wpreh, wprel, wq);
    moe_split<<<dim3(2048), dim3(256), 0, stream>>>(wgate, wgateh, wgatel, wq);
    moe_split<<<dim3(2048), dim3(256), 0, stream>>>(wpost, wposth, wpostl, wq);
    moe_ffn1_mfma<<<dim3(mt, DFF / 128, NE), dim3(512), 0, stream>>>(
        xh, xl, wpreh, wprel, wgateh, wgatel, row_tok, used_count, midh, midl, 0, cap);
    moe_ffn2_mfma<<<dim3(mt, DMODEL / 128, NE), dim3(512), 0, stream>>>(
        midh, midl, wposth, wpostl, used_count, eout, 0, cap);
  } else {
    const size_t wPE = (size_t)DFF * DMODEL;  // per-expert weight elements
    unsigned short* s0 = (unsigned short*)alloc(wPE * 2);
    unsigned short* s1 = (unsigned short*)alloc(wPE * 2);
    unsigned short* s2 = (unsigned short*)alloc(wPE * 2);
    unsigned short* s3 = (unsigned short*)alloc(wPE * 2);
    unsigned short* midh = (unsigned short*)alloc((size_t)cap * DFF * 2);
    unsigned short* midl = (unsigned short*)alloc((size_t)cap * DFF * 2);
    long wq = (long)wPE / 4;
    for (int e = 0; e < NE; ++e) {
      moe_split<<<dim3(2048), dim3(256), 0, stream>>>(wpre + (size_t)e * wPE, s0, s1, wq);
      moe_split<<<dim3(2048), dim3(256), 0, stream>>>(wgate + (size_t)e * wPE, s2, s3, wq);
      moe_ffn1_mfma<<<dim3(mt, DFF / 128, 1), dim3(512), 0, stream>>>(
          xh, xl, s0, s1, s2, s3, row_tok, used_count, midh, midl, e, cap);
      moe_split<<<dim3(2048), dim3(256), 0, stream>>>(wpost + (size_t)e * wPE, s0, s1, wq);
      moe_ffn2_mfma<<<dim3(mt, DMODEL / 128, 1), dim3(512), 0, stream>>>(
          midh, midl, s0, s1, used_count, eout, e, cap);
    }
  }
  moe_combine<<<dim3(T), dim3(256), 0, stream>>>(eout, assign_e, assign_w, assign_slot, out, cap);
}

// Round 8
// 1539.097 us; speedup vs baseline: 1.5367x; 1.5367x over previous
//
#include <hip/hip_runtime.h>
#include <math.h>

#define DMODEL 1024
#define DFF    4096
#define NE     8
#define EPSF   1.1920929e-07f

typedef float f4    __attribute__((ext_vector_type(4)));
typedef float f32x4 __attribute__((ext_vector_type(4)));
typedef short s16x8 __attribute__((ext_vector_type(8)));
typedef unsigned short u16x4 __attribute__((ext_vector_type(4)));

__device__ inline unsigned short bf16_rne(float f) {
  unsigned int u = __float_as_uint(f);
  u += 0x7fffu + ((u >> 16) & 1u);
  return (unsigned short)(u >> 16);
}
__device__ inline float bf16_up(unsigned short h) {
  return __uint_as_float(((unsigned int)h) << 16);
}

// ---------------- init ------------------------------------------------------
__global__ void moe_init(int* __restrict__ used_count, int* __restrict__ row_tok, int n_row) {
  int i = blockIdx.x * blockDim.x + threadIdx.x;
  if (i < NE) used_count[i] = 0;
  for (int j = i; j < n_row; j += gridDim.x * blockDim.x) row_tok[j] = -1;
}

// ---------------- router: softmax -> top2 -> renormalize --------------------
__global__ __launch_bounds__(256)
void moe_router(const float* __restrict__ x, const float* __restrict__ rw,
                int* __restrict__ assign_e, float* __restrict__ assign_w, int T) {
  int gw = (int)((blockIdx.x * blockDim.x + threadIdx.x) >> 6);
  int lane = threadIdx.x & 63;
  if (gw >= T) return;
  const float* h = x + (size_t)gw * DMODEL;
  float acc[NE];
#pragma unroll
  for (int e = 0; e < NE; ++e) acc[e] = 0.f;
  for (int i = lane; i < DMODEL; i += 64) {
    float hv = h[i];
#pragma unroll
    for (int e = 0; e < NE; ++e) acc[e] = fmaf(hv, rw[e * DMODEL + i], acc[e]);
  }
#pragma unroll
  for (int e = 0; e < NE; ++e) {
    float v = acc[e];
    for (int o = 32; o > 0; o >>= 1) v += __shfl_xor(v, o, 64);
    acc[e] = v;
  }
  if (lane == 0) {
    float mx = acc[0];
#pragma unroll
    for (int e = 1; e < NE; ++e) mx = fmaxf(mx, acc[e]);
    float p[NE];
    float s = 0.f;
#pragma unroll
    for (int e = 0; e < NE; ++e) { p[e] = expf(acc[e] - mx); s += p[e]; }
#pragma unroll
    for (int e = 0; e < NE; ++e) p[e] /= s;
    int e0 = 0;
#pragma unroll
    for (int e = 1; e < NE; ++e) if (p[e] > p[e0]) e0 = e;
    int e1 = (e0 == 0) ? 1 : 0;
#pragma unroll
    for (int e = 0; e < NE; ++e) { if (e != e0 && p[e] > p[e1]) e1 = e; }
    float w0 = p[e0], w1 = p[e1];
    float wsum = fmaxf(w0 + w1, EPSF);
    assign_e[2 * gw] = e0;
    assign_e[2 * gw + 1] = e1;
    assign_w[2 * gw] = w0 / wsum;
    assign_w[2 * gw + 1] = w1 / wsum;
  }
}

// ---------------- rank/capacity: stable rank within expert ------------------
__global__ __launch_bounds__(256)
void moe_rank(const int* __restrict__ assign_e, const float* __restrict__ assign_w,
              int* __restrict__ assign_slot, int* __restrict__ row_tok,
              int* __restrict__ used_count, int A, int cap) {
  int gw = (int)((blockIdx.x * blockDim.x + threadIdx.x) >> 6);
  int lane = threadIdx.x & 63;
  if (gw >= A) return;
  int e = assign_e[gw];
  float w = assign_w[gw];
  int cnt = 0;
  for (int j = lane; j < A; j += 64) {
    int ej = assign_e[j];
    float wj = assign_w[j];
    if (ej == e && (wj > w || (wj == w && j < gw))) cnt++;
  }
  for (int o = 32; o > 0; o >>= 1) cnt += __shfl_xor(cnt, o, 64);
  if (lane == 0) {
    if (cnt < cap) {
      assign_slot[gw] = cnt;
      row_tok[e * cap + cnt] = gw >> 1;
      atomicAdd(used_count + e, 1);
    } else {
      assign_slot[gw] = -1;
    }
  }
}

// ---------------- split: fp32 -> bf16 hi + bf16 lo (residual) ---------------
__global__ __launch_bounds__(256)
void moe_split(const float* __restrict__ src, unsigned short* __restrict__ hi,
               unsigned short* __restrict__ lo, long n4) {
  long i = (long)blockIdx.x * 256 + threadIdx.x;
  long stride = (long)gridDim.x * 256;
  for (; i < n4; i += stride) {
    f4 v = ((const f4*)src)[i];
    u16x4 h, l;
#pragma unroll
    for (int j = 0; j < 4; ++j) {
      unsigned short hb = bf16_rne(v[j]);
      h[j] = hb;
      l[j] = bf16_rne(v[j] - bf16_up(hb));
    }
    ((u16x4*)hi)[i] = h;
    ((u16x4*)lo)[i] = l;
  }
}

// LDS tile layout: see round-3 notes (chunk XOR swizzle, 2-way max = free)

// ---------------- ffn1: mid = pre * silu(gate), bf16x3 MFMA -----------------
__global__ __launch_bounds__(512, 2)
void moe_ffn1_mfma(const unsigned short* __restrict__ xh, const unsigned short* __restrict__ xl,
                   const unsigned short* __restrict__ wph, const unsigned short* __restrict__ wpl,
                   const unsigned short* __restrict__ wgh, const unsigned short* __restrict__ wgl,
                   const int* __restrict__ row_tok, const int* __restrict__ used_count,
                   unsigned short* __restrict__ midh, unsigned short* __restrict__ midl,
                   int e_base, int cap) {
  const int z = blockIdx.z;
  const int e = e_base + z;
  const int used = used_count[e];
  const int m0 = blockIdx.x * 128;
  if (m0 >= used) return;
  const int n0 = blockIdx.y * 128;

  __shared__ unsigned short lds[6 * 4096];  // A_h A_l P_h P_l G_h G_l

  const int tid = threadIdx.x;
  const int sr = tid >> 2;
  const int sc = (tid & 3) ^ ((tid >> 3) & 3);
  int arow = m0 + sr; if (arow >= cap) arow = cap - 1;
  int tokr = row_tok[e * cap + arow]; if (tokr < 0) tokr = 0;
  const unsigned short* gAh = xh + (size_t)tokr * DMODEL + sc * 8;
  const unsigned short* gAl = xl + (size_t)tokr * DMODEL + sc * 8;
  const size_t wrow = ((size_t)z * DFF + n0 + sr) * DMODEL + sc * 8;
  const unsigned short* gPh = wph + wrow;
  const unsigned short* gPl = wpl + wrow;
  const unsigned short* gGh = wgh + wrow;
  const unsigned short* gGl = wgl + wrow;

  const int lane = tid & 63;
  const int wid = tid >> 6;
  const int wm = wid >> 2;
  const int wn = wid & 3;
  const int lr = lane & 15;
  const int lg = lane >> 4;
  const int swz = (lr >> 1) & 3;
  const int aoff = (wm * 64 + lr) * 32 + ((lg ^ swz) * 8);
  const int boff = (wn * 32 + lr) * 32 + ((lg ^ swz) * 8);

  f32x4 accP[4][2] = {};
  f32x4 accG[4][2] = {};

  for (int kk = 0; kk < DMODEL; kk += 32) {
    s16x8 vAh = *(const s16x8*)(gAh + kk);
    s16x8 vAl = *(const s16x8*)(gAl + kk);
    s16x8 vPh = *(const s16x8*)(gPh + kk);
    s16x8 vPl = *(const s16x8*)(gPl + kk);
    s16x8 vGh = *(const s16x8*)(gGh + kk);
    s16x8 vGl = *(const s16x8*)(gGl + kk);
    __syncthreads();
    *(s16x8*)&lds[0 * 4096 + tid * 8] = vAh;
    *(s16x8*)&lds[1 * 4096 + tid * 8] = vAl;
    *(s16x8*)&lds[2 * 4096 + tid * 8] = vPh;
    *(s16x8*)&lds[3 * 4096 + tid * 8] = vPl;
    *(s16x8*)&lds[4 * 4096 + tid * 8] = vGh;
    *(s16x8*)&lds[5 * 4096 + tid * 8] = vGl;
    __syncthreads();
    s16x8 ah[4], al[4];
#pragma unroll
    for (int fm = 0; fm < 4; ++fm) {
      ah[fm] = *(const s16x8*)&lds[0 * 4096 + aoff + fm * 512];
      al[fm] = *(const s16x8*)&lds[1 * 4096 + aoff + fm * 512];
    }
#pragma unroll
    for (int fn = 0; fn < 2; ++fn) {
      s16x8 bh = *(const s16x8*)&lds[2 * 4096 + boff + fn * 512];
      s16x8 bl = *(const s16x8*)&lds[3 * 4096 + boff + fn * 512];
      s16x8 ch = *(const s16x8*)&lds[4 * 4096 + boff + fn * 512];
      s16x8 cl = *(const s16x8*)&lds[5 * 4096 + boff + fn * 512];
#pragma unroll
      for (int fm = 0; fm < 4; ++fm) {
        accP[fm][fn] = __builtin_amdgcn_mfma_f32_16x16x32_bf16(ah[fm], bh, accP[fm][fn], 0, 0, 0);
        accP[fm][fn] = __builtin_amdgcn_mfma_f32_16x16x32_bf16(ah[fm], bl, accP[fm][fn], 0, 0, 0);
        accP[fm][fn] = __builtin_amdgcn_mfma_f32_16x16x32_bf16(al[fm], bh, accP[fm][fn], 0, 0, 0);
        accG[fm][fn] = __builtin_amdgcn_mfma_f32_16x16x32_bf16(ah[fm], ch, accG[fm][fn], 0, 0, 0);
        accG[fm][fn] = __builtin_amdgcn_mfma_f32_16x16x32_bf16(ah[fm], cl, accG[fm][fn], 0, 0, 0);
        accG[fm][fn] = __builtin_amdgcn_mfma_f32_16x16x32_bf16(al[fm], ch, accG[fm][fn], 0, 0, 0);
      }
    }
  }

  // C/D: col = lane&15, row = (lane>>4)*4 + reg  [m89-verified]
#pragma unroll
  for (int fm = 0; fm < 4; ++fm)
#pragma unroll
    for (int fn = 0; fn < 2; ++fn) {
      int m = m0 + wm * 64 + fm * 16 + lg * 4;
      int n = n0 + wn * 32 + fn * 16 + lr;
#pragma unroll
      for (int r = 0; r < 4; ++r) {
        if (m + r >= cap) continue;
        float gv = accG[fm][fn][r];
        float v = accP[fm][fn][r] * (gv / (1.f + expf(-gv)));
        size_t idx = ((size_t)z * cap + (m + r)) * DFF + n;
        unsigned short hb = bf16_rne(v);
        midh[idx] = hb;
        midl[idx] = bf16_rne(v - bf16_up(hb));
      }
    }
}

// ---------------- ffn2: eout = mid @ wpost^T, bf16x3 MFMA -------------------
__global__ __launch_bounds__(512, 2)
void moe_ffn2_mfma(const unsigned short* __restrict__ midh, const unsigned short* __restrict__ midl,
                   const unsigned short* __restrict__ wh, const unsigned short* __restrict__ wl,
                   const int* __restrict__ used_count, float* __restrict__ eout,
                   int e_base, int cap) {
  const int z = blockIdx.z;
  const int e = e_base + z;
  const int used = used_count[e];
  const int m0 = blockIdx.x * 128;
  if (m0 >= used) return;
  const int n0 = blockIdx.y * 128;

  __shared__ unsigned short lds[4 * 4096];  // A_h A_l B_h B_l

  const int tid = threadIdx.x;
  const int sr = tid >> 2;
  const int sc = (tid & 3) ^ ((tid >> 3) & 3);
  int arow = m0 + sr; if (arow >= cap) arow = cap - 1;
  const unsigned short* gAh = midh + ((size_t)z * cap + arow) * DFF + sc * 8;
  const unsigned short* gAl = midl + ((size_t)z * cap + arow) * DFF + sc * 8;
  const size_t wrow = ((size_t)z * DMODEL + n0 + sr) * DFF + sc * 8;
  const unsigned short* gBh = wh + wrow;
  const unsigned short* gBl = wl + wrow;

  const int lane = tid & 63;
  const int wid = tid >> 6;
  const int wm = wid >> 2;
  const int wn = wid & 3;
  const int lr = lane & 15;
  const int lg = lane >> 4;
  const int swz = (lr >> 1) & 3;
  const int aoff = (wm * 64 + lr) * 32 + ((lg ^ swz) * 8);
  const int boff = (wn * 32 + lr) * 32 + ((lg ^ swz) * 8);

  f32x4 acc[4][2] = {};

  for (int kk = 0; kk < DFF; kk += 32) {
    s16x8 vAh = *(const s16x8*)(gAh + kk);
    s16x8 vAl = *(const s16x8*)(gAl + kk);
    s16x8 vBh = *(const s16x8*)(gBh + kk);
    s16x8 vBl = *(const s16x8*)(gBl + kk);
    __syncthreads();
    *(s16x8*)&lds[0 * 4096 + tid * 8] = vAh;
    *(s16x8*)&lds[1 * 4096 + tid * 8] = vAl;
    *(s16x8*)&lds[2 * 4096 + tid * 8] = vBh;
    *(s16x8*)&lds[3 * 4096 + tid * 8] = vBl;
    __syncthreads();
    s16x8 ah[4], al[4];
#pragma unroll
    for (int fm = 0; fm < 4; ++fm) {
      ah[fm] = *(const s16x8*)&lds[0 * 4096 + aoff + fm * 512];
      al[fm] = *(const s16x8*)&lds[1 * 4096 + aoff + fm * 512];
    }
#pragma unroll
    for (int fn = 0; fn < 2; ++fn) {
      s16x8 bh = *(const s16x8*)&lds[2 * 4096 + boff + fn * 512];
      s16x8 bl = *(const s16x8*)&lds[3 * 4096 + boff + fn * 512];
#pragma unroll
      for (int fm = 0; fm < 4; ++fm) {
        acc[fm][fn] = __builtin_amdgcn_mfma_f32_16x16x32_bf16(ah[fm], bh, acc[fm][fn], 0, 0, 0);
        acc[fm][fn] = __builtin_amdgcn_mfma_f32_16x16x32_bf16(ah[fm], bl, acc[fm][fn], 0, 0, 0);
        acc[fm][fn] = __builtin_amdgcn_mfma_f32_16x16x32_bf16(al[fm], bh, acc[fm][fn], 0, 0, 0);
      }
    }
  }

#pragma unroll
  for (int fm = 0; fm < 4; ++fm)
#pragma unroll
    for (int fn = 0; fn < 2; ++fn) {
      int m = m0 + wm * 64 + fm * 16 + lg * 4;
      int n = n0 + wn * 32 + fn * 16 + lr;
#pragma unroll
      for (int r = 0; r < 4; ++r) {
        if (m + r >= cap) continue;
        eout[((size_t)e * cap + (m + r)) * DMODEL + n] = acc[fm][fn][r];
      }
    }
}

// ---------------- combine ---------------------------------------------------
__global__ __launch_bounds__(256)
void moe_combine(const float* __restrict__ eout, const int* __restrict__ assign_e,
                 const float* __restrict__ assign_w, const int* __restrict__ assign_slot,
                 float* __restrict__ out, int cap) {
  int t = blockIdx.x;
  int e0 = assign_e[2 * t], e1 = assign_e[2 * t + 1];
  float w0 = assign_w[2 * t], w1 = assign_w[2 * t + 1];
  int s0 = assign_slot[2 * t], s1 = assign_slot[2 * t + 1];
  float k0 = (s0 >= 0) ? w0 : 0.f;
  float k1 = (s1 >= 0) ? w1 : 0.f;
  float wsum = fmaxf(k0 + k1, EPSF);
  k0 /= wsum;
  k1 /= wsum;
  int i = threadIdx.x * 4;
  f4 v = {0.f, 0.f, 0.f, 0.f};
  if (s0 >= 0) v += k0 * *(const f4*)(eout + ((size_t)e0 * cap + s0) * DMODEL + i);
  if (s1 >= 0) v += k1 * *(const f4*)(eout + ((size_t)e1 * cap + s1) * DMODEL + i);
  *(f4*)(out + (size_t)t * DMODEL + i) = v;
}

extern "C" void kernel_launch(void* const* d_in, const int* in_sizes, int n_in,
                              void* d_out, int out_size, void* d_ws, size_t ws_size,
                              hipStream_t stream) {
  const float* x     = (const float*)d_in[0];
  const float* rw    = (const float*)d_in[1];
  const float* wpre  = (const float*)d_in[2];
  const float* wgate = (const float*)d_in[3];
  const float* wpost = (const float*)d_in[4];
  float* out = (float*)d_out;

  const int T = in_sizes[0] / DMODEL;
  const int A = T * 2;
  int cap = (int)ceil(1.25 * (double)A / NE);
  if (cap < 1) cap = 1;

  char* ws = (char*)d_ws;
  size_t off = 0;
  auto alloc = [&](size_t bytes) -> void* {
    void* p = ws + off;
    off += (bytes + 255) & ~(size_t)255;
    return p;
  };
  int*   assign_e    = (int*)alloc((size_t)A * 4);
  float* assign_w    = (float*)alloc((size_t)A * 4);
  int*   assign_slot = (int*)alloc((size_t)A * 4);
  int*   used_count  = (int*)alloc(NE * 4);
  int*   row_tok     = (int*)alloc((size_t)NE * cap * 4);
  float* eout        = (float*)alloc((size_t)NE * cap * DMODEL * 4);
  unsigned short* xh = (unsigned short*)alloc((size_t)T * DMODEL * 2);
  unsigned short* xl = (unsigned short*)alloc((size_t)T * DMODEL * 2);

  // ---- group-size selection: largest G (power of 2) whose slabs fit ws ----
  // slabs needed: 4 weight slabs (A_h,A_l,B_h,B_l) of G*wPE elems (2B each)
  // + mid hi/lo of G*cap*DFF elems (2B each). Split order reuses slab A for
  // wpost after ffn1 (stream-ordered: ffn1 drains before split(post) runs),
  // so 4 slabs suffice for all 3 weight tensors.
  const size_t wPE = (size_t)DFF * DMODEL;
  auto al256 = [](size_t b) { return (b + 255) & ~(size_t)255; };
  int G = NE;
  while (G > 1) {
    size_t slab = al256((size_t)G * wPE * 2);
    size_t mids = al256((size_t)G * cap * DFF * 2);
    if (off + 4 * slab + 2 * mids + 65536 <= ws_size) break;
    G >>= 1;
  }
  unsigned short* sAh  = (unsigned short*)alloc((size_t)G * wPE * 2);
  unsigned short* sAl  = (unsigned short*)alloc((size_t)G * wPE * 2);
  unsigned short* sBh  = (unsigned short*)alloc((size_t)G * wPE * 2);
  unsigned short* sBl  = (unsigned short*)alloc((size_t)G * wPE * 2);
  unsigned short* midh = (unsigned short*)alloc((size_t)G * cap * DFF * 2);
  unsigned short* midl = (unsigned short*)alloc((size_t)G * cap * DFF * 2);

  const int n_row = NE * cap;
  moe_init<<<dim3((n_row + 255) / 256), dim3(256), 0, stream>>>(used_count, row_tok, n_row);
  moe_router<<<dim3((T + 3) / 4), dim3(256), 0, stream>>>(x, rw, assign_e, assign_w, T);
  moe_rank<<<dim3((A + 3) / 4), dim3(256), 0, stream>>>(assign_e, assign_w, assign_slot,
                                                        row_tok, used_count, A, cap);
  long xq = (long)T * DMODEL / 4;
  moe_split<<<dim3((unsigned)((xq + 255) / 256 > 2048 ? 2048 : (xq + 255) / 256)),
              dim3(256), 0, stream>>>(x, xh, xl, xq);

  const int mt = (cap + 127) / 128;
  for (int g0 = 0; g0 < NE; g0 += G) {
    long wq = (long)G * wPE / 4;
    moe_split<<<dim3(2048), dim3(256), 0, stream>>>(wpre + (size_t)g0 * wPE, sAh, sAl, wq);
    moe_split<<<dim3(2048), dim3(256), 0, stream>>>(wgate + (size_t)g0 * wPE, sBh, sBl, wq);
    moe_ffn1_mfma<<<dim3(mt, DFF / 128, G), dim3(512), 0, stream>>>(
        xh, xl, sAh, sAl, sBh, sBl, row_tok, used_count, midh, midl, g0, cap);
    moe_split<<<dim3(2048), dim3(256), 0, stream>>>(wpost + (size_t)g0 * wPE, sAh, sAl, wq);
    moe_ffn2_mfma<<<dim3(mt, DMODEL / 128, G), dim3(512), 0, stream>>>(
        midh, midl, sAh, sAl, used_count, eout, g0, cap);
  }
  moe_combine<<<dim3(T), dim3(256), 0, stream>>>(eout, assign_e, assign_w, assign_slot, out, cap);
}

// Round 9
// 1332.587 us; speedup vs baseline: 1.7748x; 1.1550x over previous
//
#include <hip/hip_runtime.h>
#include <math.h>

#define DMODEL 1024
#define DFF    4096
#define NE     8
#define EPSF   1.1920929e-07f

typedef float f4    __attribute__((ext_vector_type(4)));
typedef float f32x4 __attribute__((ext_vector_type(4)));
typedef short s16x8 __attribute__((ext_vector_type(8)));
typedef unsigned short u16x4 __attribute__((ext_vector_type(4)));

__device__ inline unsigned short bf16_rne(float f) {
  unsigned int u = __float_as_uint(f);
  u += 0x7fffu + ((u >> 16) & 1u);
  return (unsigned short)(u >> 16);
}
__device__ inline float bf16_up(unsigned short h) {
  return __uint_as_float(((unsigned int)h) << 16);
}

// XCD-aware flat-grid decode: dispatch round-robins d%8 across XCDs [m09/m157].
// All `mt` m-blocks of one weight panel (by,z) get the same d%8 -> same XCD L2;
// panels are n-contiguous per XCD (expert-per-XCD at G=8).
__device__ inline void xcd_decode(int d, int nw, int mt, int ntiles,
                                  int& bx, int& by, int& z) {
  int S = nw >> 3;                   // slots per xcd; nw%8==0 guaranteed
  int xcd = d & 7;
  int slot = d >> 3;
  int panel = xcd * (S / mt) + slot / mt;
  bx = slot % mt;
  by = panel % ntiles;
  z = panel / ntiles;
}

// ---------------- init ------------------------------------------------------
__global__ void moe_init(int* __restrict__ used_count, int* __restrict__ row_tok, int n_row) {
  int i = blockIdx.x * blockDim.x + threadIdx.x;
  if (i < NE) used_count[i] = 0;
  for (int j = i; j < n_row; j += gridDim.x * blockDim.x) row_tok[j] = -1;
}

// ---------------- router: softmax -> top2 -> renormalize --------------------
__global__ __launch_bounds__(256)
void moe_router(const float* __restrict__ x, const float* __restrict__ rw,
                int* __restrict__ assign_e, float* __restrict__ assign_w, int T) {
  int gw = (int)((blockIdx.x * blockDim.x + threadIdx.x) >> 6);
  int lane = threadIdx.x & 63;
  if (gw >= T) return;
  const float* h = x + (size_t)gw * DMODEL;
  float acc[NE];
#pragma unroll
  for (int e = 0; e < NE; ++e) acc[e] = 0.f;
  for (int i = lane; i < DMODEL; i += 64) {
    float hv = h[i];
#pragma unroll
    for (int e = 0; e < NE; ++e) acc[e] = fmaf(hv, rw[e * DMODEL + i], acc[e]);
  }
#pragma unroll
  for (int e = 0; e < NE; ++e) {
    float v = acc[e];
    for (int o = 32; o > 0; o >>= 1) v += __shfl_xor(v, o, 64);
    acc[e] = v;
  }
  if (lane == 0) {
    float mx = acc[0];
#pragma unroll
    for (int e = 1; e < NE; ++e) mx = fmaxf(mx, acc[e]);
    float p[NE];
    float s = 0.f;
#pragma unroll
    for (int e = 0; e < NE; ++e) { p[e] = expf(acc[e] - mx); s += p[e]; }
#pragma unroll
    for (int e = 0; e < NE; ++e) p[e] /= s;
    int e0 = 0;
#pragma unroll
    for (int e = 1; e < NE; ++e) if (p[e] > p[e0]) e0 = e;
    int e1 = (e0 == 0) ? 1 : 0;
#pragma unroll
    for (int e = 0; e < NE; ++e) { if (e != e0 && p[e] > p[e1]) e1 = e; }
    float w0 = p[e0], w1 = p[e1];
    float wsum = fmaxf(w0 + w1, EPSF);
    assign_e[2 * gw] = e0;
    assign_e[2 * gw + 1] = e1;
    assign_w[2 * gw] = w0 / wsum;
    assign_w[2 * gw + 1] = w1 / wsum;
  }
}

// ---------------- rank/capacity: stable rank within expert ------------------
__global__ __launch_bounds__(256)
void moe_rank(const int* __restrict__ assign_e, const float* __restrict__ assign_w,
              int* __restrict__ assign_slot, int* __restrict__ row_tok,
              int* __restrict__ used_count, int A, int cap) {
  int gw = (int)((blockIdx.x * blockDim.x + threadIdx.x) >> 6);
  int lane = threadIdx.x & 63;
  if (gw >= A) return;
  int e = assign_e[gw];
  float w = assign_w[gw];
  int cnt = 0;
  for (int j = lane; j < A; j += 64) {
    int ej = assign_e[j];
    float wj = assign_w[j];
    if (ej == e && (wj > w || (wj == w && j < gw))) cnt++;
  }
  for (int o = 32; o > 0; o >>= 1) cnt += __shfl_xor(cnt, o, 64);
  if (lane == 0) {
    if (cnt < cap) {
      assign_slot[gw] = cnt;
      row_tok[e * cap + cnt] = gw >> 1;
      atomicAdd(used_count + e, 1);
    } else {
      assign_slot[gw] = -1;
    }
  }
}

// ---------------- split: fp32 -> bf16 hi + bf16 lo (residual) ---------------
__global__ __launch_bounds__(256)
void moe_split(const float* __restrict__ src, unsigned short* __restrict__ hi,
               unsigned short* __restrict__ lo, long n4) {
  long i = (long)blockIdx.x * 256 + threadIdx.x;
  long stride = (long)gridDim.x * 256;
  for (; i < n4; i += stride) {
    f4 v = ((const f4*)src)[i];
    u16x4 h, l;
#pragma unroll
    for (int j = 0; j < 4; ++j) {
      unsigned short hb = bf16_rne(v[j]);
      h[j] = hb;
      l[j] = bf16_rne(v[j] - bf16_up(hb));
    }
    ((u16x4*)hi)[i] = h;
    ((u16x4*)lo)[i] = l;
  }
}

// LDS tile layout: see round-3 notes (chunk XOR swizzle, 2-way max = free)

// ---------------- ffn1: mid = pre * silu(gate), bf16x3 MFMA -----------------
__global__ __launch_bounds__(512, 2)
void moe_ffn1_mfma(const unsigned short* __restrict__ xh, const unsigned short* __restrict__ xl,
                   const unsigned short* __restrict__ wph, const unsigned short* __restrict__ wpl,
                   const unsigned short* __restrict__ wgh, const unsigned short* __restrict__ wgl,
                   const int* __restrict__ row_tok, const int* __restrict__ used_count,
                   unsigned short* __restrict__ midh, unsigned short* __restrict__ midl,
                   int e_base, int cap, int mt) {
  int bx, by, z;
  xcd_decode(blockIdx.x, gridDim.x, mt, DFF / 128, bx, by, z);
  const int e = e_base + z;
  const int used = used_count[e];
  const int m0 = bx * 128;
  if (m0 >= used) return;
  const int n0 = by * 128;

  __shared__ unsigned short lds[6 * 4096];  // A_h A_l P_h P_l G_h G_l

  const int tid = threadIdx.x;
  const int sr = tid >> 2;
  const int sc = (tid & 3) ^ ((tid >> 3) & 3);
  int arow = m0 + sr; if (arow >= cap) arow = cap - 1;
  int tokr = row_tok[e * cap + arow]; if (tokr < 0) tokr = 0;
  const unsigned short* gAh = xh + (size_t)tokr * DMODEL + sc * 8;
  const unsigned short* gAl = xl + (size_t)tokr * DMODEL + sc * 8;
  const size_t wrow = ((size_t)z * DFF + n0 + sr) * DMODEL + sc * 8;
  const unsigned short* gPh = wph + wrow;
  const unsigned short* gPl = wpl + wrow;
  const unsigned short* gGh = wgh + wrow;
  const unsigned short* gGl = wgl + wrow;

  const int lane = tid & 63;
  const int wid = tid >> 6;
  const int wm = wid >> 2;
  const int wn = wid & 3;
  const int lr = lane & 15;
  const int lg = lane >> 4;
  const int swz = (lr >> 1) & 3;
  const int aoff = (wm * 64 + lr) * 32 + ((lg ^ swz) * 8);
  const int boff = (wn * 32 + lr) * 32 + ((lg ^ swz) * 8);

  f32x4 accP[4][2] = {};
  f32x4 accG[4][2] = {};

  // register prefetch (T14): issue next K-step loads between barrier and MFMA
  s16x8 vAh = *(const s16x8*)(gAh);
  s16x8 vAl = *(const s16x8*)(gAl);
  s16x8 vPh = *(const s16x8*)(gPh);
  s16x8 vPl = *(const s16x8*)(gPl);
  s16x8 vGh = *(const s16x8*)(gGh);
  s16x8 vGl = *(const s16x8*)(gGl);

  for (int kk = 0; kk < DMODEL; kk += 32) {
    __syncthreads();
    *(s16x8*)&lds[0 * 4096 + tid * 8] = vAh;
    *(s16x8*)&lds[1 * 4096 + tid * 8] = vAl;
    *(s16x8*)&lds[2 * 4096 + tid * 8] = vPh;
    *(s16x8*)&lds[3 * 4096 + tid * 8] = vPl;
    *(s16x8*)&lds[4 * 4096 + tid * 8] = vGh;
    *(s16x8*)&lds[5 * 4096 + tid * 8] = vGl;
    if (kk + 32 < DMODEL) {
      vAh = *(const s16x8*)(gAh + kk + 32);
      vAl = *(const s16x8*)(gAl + kk + 32);
      vPh = *(const s16x8*)(gPh + kk + 32);
      vPl = *(const s16x8*)(gPl + kk + 32);
      vGh = *(const s16x8*)(gGh + kk + 32);
      vGl = *(const s16x8*)(gGl + kk + 32);
    }
    __syncthreads();
    s16x8 ah[4], al[4];
#pragma unroll
    for (int fm = 0; fm < 4; ++fm) {
      ah[fm] = *(const s16x8*)&lds[0 * 4096 + aoff + fm * 512];
      al[fm] = *(const s16x8*)&lds[1 * 4096 + aoff + fm * 512];
    }
#pragma unroll
    for (int fn = 0; fn < 2; ++fn) {
      s16x8 bh = *(const s16x8*)&lds[2 * 4096 + boff + fn * 512];
      s16x8 bl = *(const s16x8*)&lds[3 * 4096 + boff + fn * 512];
      s16x8 ch = *(const s16x8*)&lds[4 * 4096 + boff + fn * 512];
      s16x8 cl = *(const s16x8*)&lds[5 * 4096 + boff + fn * 512];
#pragma unroll
      for (int fm = 0; fm < 4; ++fm) {
        accP[fm][fn] = __builtin_amdgcn_mfma_f32_16x16x32_bf16(ah[fm], bh, accP[fm][fn], 0, 0, 0);
        accP[fm][fn] = __builtin_amdgcn_mfma_f32_16x16x32_bf16(ah[fm], bl, accP[fm][fn], 0, 0, 0);
        accP[fm][fn] = __builtin_amdgcn_mfma_f32_16x16x32_bf16(al[fm], bh, accP[fm][fn], 0, 0, 0);
        accG[fm][fn] = __builtin_amdgcn_mfma_f32_16x16x32_bf16(ah[fm], ch, accG[fm][fn], 0, 0, 0);
        accG[fm][fn] = __builtin_amdgcn_mfma_f32_16x16x32_bf16(ah[fm], cl, accG[fm][fn], 0, 0, 0);
        accG[fm][fn] = __builtin_amdgcn_mfma_f32_16x16x32_bf16(al[fm], ch, accG[fm][fn], 0, 0, 0);
      }
    }
  }

  // C/D: col = lane&15, row = (lane>>4)*4 + reg  [m89-verified]
#pragma unroll
  for (int fm = 0; fm < 4; ++fm)
#pragma unroll
    for (int fn = 0; fn < 2; ++fn) {
      int m = m0 + wm * 64 + fm * 16 + lg * 4;
      int n = n0 + wn * 32 + fn * 16 + lr;
#pragma unroll
      for (int r = 0; r < 4; ++r) {
        if (m + r >= cap) continue;
        float gv = accG[fm][fn][r];
        float v = accP[fm][fn][r] * (gv / (1.f + expf(-gv)));
        size_t idx = ((size_t)z * cap + (m + r)) * DFF + n;
        unsigned short hb = bf16_rne(v);
        midh[idx] = hb;
        midl[idx] = bf16_rne(v - bf16_up(hb));
      }
    }
}

// ---------------- ffn2: eout = mid @ wpost^T, bf16x3 MFMA -------------------
__global__ __launch_bounds__(512, 2)
void moe_ffn2_mfma(const unsigned short* __restrict__ midh, const unsigned short* __restrict__ midl,
                   const unsigned short* __restrict__ wh, const unsigned short* __restrict__ wl,
                   const int* __restrict__ used_count, float* __restrict__ eout,
                   int e_base, int cap, int mt) {
  int bx, by, z;
  xcd_decode(blockIdx.x, gridDim.x, mt, DMODEL / 128, bx, by, z);
  const int e = e_base + z;
  const int used = used_count[e];
  const int m0 = bx * 128;
  if (m0 >= used) return;
  const int n0 = by * 128;

  __shared__ unsigned short lds[4 * 4096];  // A_h A_l B_h B_l

  const int tid = threadIdx.x;
  const int sr = tid >> 2;
  const int sc = (tid & 3) ^ ((tid >> 3) & 3);
  int arow = m0 + sr; if (arow >= cap) arow = cap - 1;
  const unsigned short* gAh = midh + ((size_t)z * cap + arow) * DFF + sc * 8;
  const unsigned short* gAl = midl + ((size_t)z * cap + arow) * DFF + sc * 8;
  const size_t wrow = ((size_t)z * DMODEL + n0 + sr) * DFF + sc * 8;
  const unsigned short* gBh = wh + wrow;
  const unsigned short* gBl = wl + wrow;

  const int lane = tid & 63;
  const int wid = tid >> 6;
  const int wm = wid >> 2;
  const int wn = wid & 3;
  const int lr = lane & 15;
  const int lg = lane >> 4;
  const int swz = (lr >> 1) & 3;
  const int aoff = (wm * 64 + lr) * 32 + ((lg ^ swz) * 8);
  const int boff = (wn * 32 + lr) * 32 + ((lg ^ swz) * 8);

  f32x4 acc[4][2] = {};

  s16x8 vAh = *(const s16x8*)(gAh);
  s16x8 vAl = *(const s16x8*)(gAl);
  s16x8 vBh = *(const s16x8*)(gBh);
  s16x8 vBl = *(const s16x8*)(gBl);

  for (int kk = 0; kk < DFF; kk += 32) {
    __syncthreads();
    *(s16x8*)&lds[0 * 4096 + tid * 8] = vAh;
    *(s16x8*)&lds[1 * 4096 + tid * 8] = vAl;
    *(s16x8*)&lds[2 * 4096 + tid * 8] = vBh;
    *(s16x8*)&lds[3 * 4096 + tid * 8] = vBl;
    if (kk + 32 < DFF) {
      vAh = *(const s16x8*)(gAh + kk + 32);
      vAl = *(const s16x8*)(gAl + kk + 32);
      vBh = *(const s16x8*)(gBh + kk + 32);
      vBl = *(const s16x8*)(gBl + kk + 32);
    }
    __syncthreads();
    s16x8 ah[4], al[4];
#pragma unroll
    for (int fm = 0; fm < 4; ++fm) {
      ah[fm] = *(const s16x8*)&lds[0 * 4096 + aoff + fm * 512];
      al[fm] = *(const s16x8*)&lds[1 * 4096 + aoff + fm * 512];
    }
#pragma unroll
    for (int fn = 0; fn < 2; ++fn) {
      s16x8 bh = *(const s16x8*)&lds[2 * 4096 + boff + fn * 512];
      s16x8 bl = *(const s16x8*)&lds[3 * 4096 + boff + fn * 512];
#pragma unroll
      for (int fm = 0; fm < 4; ++fm) {
        acc[fm][fn] = __builtin_amdgcn_mfma_f32_16x16x32_bf16(ah[fm], bh, acc[fm][fn], 0, 0, 0);
        acc[fm][fn] = __builtin_amdgcn_mfma_f32_16x16x32_bf16(ah[fm], bl, acc[fm][fn], 0, 0, 0);
        acc[fm][fn] = __builtin_amdgcn_mfma_f32_16x16x32_bf16(al[fm], bh, acc[fm][fn], 0, 0, 0);
      }
    }
  }

#pragma unroll
  for (int fm = 0; fm < 4; ++fm)
#pragma unroll
    for (int fn = 0; fn < 2; ++fn) {
      int m = m0 + wm * 64 + fm * 16 + lg * 4;
      int n = n0 + wn * 32 + fn * 16 + lr;
#pragma unroll
      for (int r = 0; r < 4; ++r) {
        if (m + r >= cap) continue;
        eout[((size_t)e * cap + (m + r)) * DMODEL + n] = acc[fm][fn][r];
      }
    }
}

// ---------------- combine ---------------------------------------------------
__global__ __launch_bounds__(256)
void moe_combine(const float* __restrict__ eout, const int* __restrict__ assign_e,
                 const float* __restrict__ assign_w, const int* __restrict__ assign_slot,
                 float* __restrict__ out, int cap) {
  int t = blockIdx.x;
  int e0 = assign_e[2 * t], e1 = assign_e[2 * t + 1];
  float w0 = assign_w[2 * t], w1 = assign_w[2 * t + 1];
  int s0 = assign_slot[2 * t], s1 = assign_slot[2 * t + 1];
  float k0 = (s0 >= 0) ? w0 : 0.f;
  float k1 = (s1 >= 0) ? w1 : 0.f;
  float wsum = fmaxf(k0 + k1, EPSF);
  k0 /= wsum;
  k1 /= wsum;
  int i = threadIdx.x * 4;
  f4 v = {0.f, 0.f, 0.f, 0.f};
  if (s0 >= 0) v += k0 * *(const f4*)(eout + ((size_t)e0 * cap + s0) * DMODEL + i);
  if (s1 >= 0) v += k1 * *(const f4*)(eout + ((size_t)e1 * cap + s1) * DMODEL + i);
  *(f4*)(out + (size_t)t * DMODEL + i) = v;
}

extern "C" void kernel_launch(void* const* d_in, const int* in_sizes, int n_in,
                              void* d_out, int out_size, void* d_ws, size_t ws_size,
                              hipStream_t stream) {
  const float* x     = (const float*)d_in[0];
  const float* rw    = (const float*)d_in[1];
  const float* wpre  = (const float*)d_in[2];
  const float* wgate = (const float*)d_in[3];
  const float* wpost = (const float*)d_in[4];
  float* out = (float*)d_out;

  const int T = in_sizes[0] / DMODEL;
  const int A = T * 2;
  int cap = (int)ceil(1.25 * (double)A / NE);
  if (cap < 1) cap = 1;

  char* ws = (char*)d_ws;
  size_t off = 0;
  auto alloc = [&](size_t bytes) -> void* {
    void* p = ws + off;
    off += (bytes + 255) & ~(size_t)255;
    return p;
  };
  int*   assign_e    = (int*)alloc((size_t)A * 4);
  float* assign_w    = (float*)alloc((size_t)A * 4);
  int*   assign_slot = (int*)alloc((size_t)A * 4);
  int*   used_count  = (int*)alloc(NE * 4);
  int*   row_tok     = (int*)alloc((size_t)NE * cap * 4);
  float* eout        = (float*)alloc((size_t)NE * cap * DMODEL * 4);
  unsigned short* xh = (unsigned short*)alloc((size_t)T * DMODEL * 2);
  unsigned short* xl = (unsigned short*)alloc((size_t)T * DMODEL * 2);

  const size_t wPE = (size_t)DFF * DMODEL;
  auto al256 = [](size_t b) { return (b + 255) & ~(size_t)255; };
  int G = NE;
  while (G > 1) {
    size_t slab = al256((size_t)G * wPE * 2);
    size_t mids = al256((size_t)G * cap * DFF * 2);
    if (off + 4 * slab + 2 * mids + 65536 <= ws_size) break;
    G >>= 1;
  }
  unsigned short* sAh  = (unsigned short*)alloc((size_t)G * wPE * 2);
  unsigned short* sAl  = (unsigned short*)alloc((size_t)G * wPE * 2);
  unsigned short* sBh  = (unsigned short*)alloc((size_t)G * wPE * 2);
  unsigned short* sBl  = (unsigned short*)alloc((size_t)G * wPE * 2);
  unsigned short* midh = (unsigned short*)alloc((size_t)G * cap * DFF * 2);
  unsigned short* midl = (unsigned short*)alloc((size_t)G * cap * DFF * 2);

  const int n_row = NE * cap;
  moe_init<<<dim3((n_row + 255) / 256), dim3(256), 0, stream>>>(used_count, row_tok, n_row);
  moe_router<<<dim3((T + 3) / 4), dim3(256), 0, stream>>>(x, rw, assign_e, assign_w, T);
  moe_rank<<<dim3((A + 3) / 4), dim3(256), 0, stream>>>(assign_e, assign_w, assign_slot,
                                                        row_tok, used_count, A, cap);
  long xq = (long)T * DMODEL / 4;
  moe_split<<<dim3((unsigned)((xq + 255) / 256 > 2048 ? 2048 : (xq + 255) / 256)),
              dim3(256), 0, stream>>>(x, xh, xl, xq);

  const int mt = (cap + 127) / 128;
  for (int g0 = 0; g0 < NE; g0 += G) {
    long wq = (long)G * wPE / 4;
    moe_split<<<dim3(2048), dim3(256), 0, stream>>>(wpre + (size_t)g0 * wPE, sAh, sAl, wq);
    moe_split<<<dim3(2048), dim3(256), 0, stream>>>(wgate + (size_t)g0 * wPE, sBh, sBl, wq);
    moe_ffn1_mfma<<<dim3(mt * (DFF / 128) * G), dim3(512), 0, stream>>>(
        xh, xl, sAh, sAl, sBh, sBl, row_tok, used_count, midh, midl, g0, cap, mt);
    moe_split<<<dim3(2048), dim3(256), 0, stream>>>(wpost + (size_t)g0 * wPE, sAh, sAl, wq);
    moe_ffn2_mfma<<<dim3(mt * (DMODEL / 128) * G), dim3(512), 0, stream>>>(
        midh, midl, sAh, sAl, used_count, eout, g0, cap, mt);
  }
  moe_combine<<<dim3(T), dim3(256), 0, stream>>>(eout, assign_e, assign_w, assign_slot, out, cap);
}